// Round 12
// baseline (458.789 us; speedup 1.0000x reference)
//
#include <hip/hip_runtime.h>
#include <stdint.h>

#define N_NODES 20000
#define E_EDGES 160000
#define C_DIM 32
#define OUT_DIM 128
#define K_REAL 910
#define KPH 480           // padded per-half K (455 real + 25 zeros), 15 x 32
#define DEG_CAP 64
#define SEG 1024
#define NSEG 20           // ceil(20000/1024)

typedef __attribute__((ext_vector_type(4))) float f32x4;
typedef __attribute__((ext_vector_type(8))) short short8;

__device__ __forceinline__ float bf2f(unsigned short u){
  union { unsigned int i; float f; } v; v.i = ((unsigned int)u) << 16; return v.f;
}
__device__ __forceinline__ unsigned short f2bf(float f){
  union { float f; unsigned int i; } v; v.f = f;
  unsigned int i = v.i;
  unsigned int r = (i + 0x7FFFu + ((i >> 16) & 1u)) >> 16;
  return (unsigned short)r;
}
__device__ __forceinline__ float ldv(const void* p, size_t i, int isbf){
  return isbf ? bf2f(((const unsigned short*)p)[i]) : ((const float*)p)[i];
}
__device__ __forceinline__ int clampi(int v, int hi){  // [0, hi)
  return ((unsigned)v < (unsigned)hi) ? v : 0;
}

// ---------------- dtype sniffer ----------------
__global__ void k_sniff(const void* xraw, int* flag){
  const unsigned short* xu = (const unsigned short*)xraw;
  __shared__ int s_bad;
  int tid = threadIdx.x;
  if (tid == 0) s_bad = 0;
  __syncthreads();
  float v = bf2f(xu[tid * 2499]);
  if (!(fabsf(v) < 100.0f)) s_bad = 1;
  __syncthreads();
  if (tid == 0) flag[0] = s_bad ? 0 : 1; // 1 = bf16, 0 = fp32
}

__global__ void k_zero(int* p, int n){
  int i = blockIdx.x*blockDim.x + threadIdx.x;
  if (i < n) p[i] = 0;
}

// ---------------- edge vectors + degree histograms ----------------
__global__ void k_build(const void* __restrict__ pos,
                        const int* __restrict__ row, const int* __restrict__ col,
                        float* __restrict__ vecn, int* __restrict__ cnt,
                        const int* __restrict__ flg)
{
  int e = blockIdx.x*blockDim.x + threadIdx.x;
  if (e >= E_EDGES) return;
  int isbf = flg[0];
  int r = clampi(row[e], N_NODES), c = clampi(col[e], N_NODES);
  float vx = ldv(pos, (size_t)c*3+0, isbf) - ldv(pos, (size_t)r*3+0, isbf);
  float vy = ldv(pos, (size_t)c*3+1, isbf) - ldv(pos, (size_t)r*3+1, isbf);
  float vz = ldv(pos, (size_t)c*3+2, isbf) - ldv(pos, (size_t)r*3+2, isbf);
  float nn = sqrtf(vx*vx + vy*vy + vz*vz);
  f32x4 vv; vv[0]=vx; vv[1]=vy; vv[2]=vz; vv[3]=nn;
  *(f32x4*)(vecn + (size_t)e*4) = vv;
  atomicAdd(cnt + r, 1);
  atomicAdd(cnt + N_NODES + c, 1);
}

// ---------------- 3-phase exclusive scan over cnt[2N] ----------------
__global__ void k_scan1(const int* __restrict__ cnt, int* __restrict__ start2,
                        int* __restrict__ segsum){
  __shared__ int buf[SEG];
  int b = blockIdx.x, arr = b / NSEG, seg = b - arr*NSEG;
  const int* cntp = cnt + (size_t)arr*N_NODES;
  int* startp = start2 + (size_t)arr*(N_NODES+1);
  int tid = threadIdx.x;
  int i = seg*SEG + tid;
  int v = (i < N_NODES) ? cntp[i] : 0;
  buf[tid] = v;
  __syncthreads();
  for (int off = 1; off < SEG; off <<= 1){
    int t = (tid >= off) ? buf[tid-off] : 0;
    __syncthreads();
    buf[tid] += t;
    __syncthreads();
  }
  if (i < N_NODES) startp[i] = buf[tid] - v;
  if (tid == SEG-1) segsum[b] = buf[tid];
}
__global__ void k_scan2(int* segsum){
  int tid = threadIdx.x;
  if (tid < 2){
    int run = 0;
    for (int s = 0; s < NSEG; ++s){
      int v = segsum[tid*NSEG+s]; segsum[tid*NSEG+s] = run; run += v;
    }
  }
}
__global__ void k_scan3(int* __restrict__ start2, int* __restrict__ fill2,
                        const int* __restrict__ segsum){
  int b = blockIdx.x, arr = b / NSEG, seg = b - arr*NSEG;
  int* startp = start2 + (size_t)arr*(N_NODES+1);
  int* fillp  = fill2  + (size_t)arr*N_NODES;
  int tid = threadIdx.x;
  int i = seg*SEG + tid;
  int add = segsum[b];
  if (i < N_NODES){ int s = startp[i] + add; startp[i] = s; fillp[i] = s; }
  if (b == 0 && tid == 0){
    start2[N_NODES] = E_EDGES;
    start2[(N_NODES+1) + N_NODES] = E_EDGES;
  }
}

// ---------------- scatter edge ids into CSR lists (+ inverse col perm + node of pos) ----------------
__global__ void k_scatter(const int* __restrict__ row, const int* __restrict__ col,
                          int* fill2, int* list_row, int* list_col,
                          int* pos_col, int* node_of_pos)
{
  int e = blockIdx.x*blockDim.x + threadIdx.x;
  if (e >= E_EDGES) return;
  int r = clampi(row[e], N_NODES), c = clampi(col[e], N_NODES);
  int p = atomicAdd(fill2 + r, 1);
  if ((unsigned)p < E_EDGES) list_row[p] = e;
  int q = atomicAdd(fill2 + N_NODES + c, 1);
  if ((unsigned)q < E_EDGES){ list_col[q] = e; node_of_pos[q] = c; }
  pos_col[e] = clampi(q, E_EDGES);
}

// ---------------- pack W into two padded halves Wp[half][128][KPH] ----------------
__global__ void k_packw(const void* __restrict__ W, unsigned short* __restrict__ Wp,
                        const int* __restrict__ flg){
  int isbf = flg[0];
  int i = blockIdx.x*blockDim.x + threadIdx.x;
  if (i >= 2*OUT_DIM*KPH) return;
  int half = i / (OUT_DIM*KPH);
  int rem = i - half*OUT_DIM*KPH;
  int o = rem / KPH, kp = rem - o*KPH;
  float v = 0.f;
  if (kp < 455){
    int t = kp/65, f = kp - t*65;
    v = ldv(W, (size_t)o*K_REAL + (2*t + half)*65 + f, isbf);
  }
  Wp[i] = f2bf(v);
}

// ---------------- node-centric message build (float fS, u32 bins, x4 unroll) ----------------
__global__ __launch_bounds__(256)
void k_msg_node(const void* __restrict__ x, const void* __restrict__ eattr,
                const float* __restrict__ vecn,
                const int* __restrict__ row, const int* __restrict__ col,
                const int* __restrict__ start2,
                const int* __restrict__ list_row, const int* __restrict__ list_col,
                const int* __restrict__ pos_col,
                unsigned short* __restrict__ msg,
                const int* __restrict__ flg, int half)
{
  __shared__ int posT[DEG_CAP];
  __shared__ int othS[DEG_CAP];
  __shared__ float vS[DEG_CAP][4], vT[DEG_CAP][4];
  __shared__ float eS[DEG_CAP];
  __shared__ float fS[DEG_CAP][64];                // float: convert once at staging
  __shared__ float e64[DEG_CAP][8];
  __shared__ unsigned char bins[DEG_CAP][DEG_CAP]; // [target][source], 0-padded

  const float cb1 = 0.9009688679f, cb2 = 0.6234898019f, cb3 = 0.2225209340f;
  const int* start_row = start2;
  const int* start_col = start2 + (N_NODES+1);
  int j = blockIdx.x;
  int tid = threadIdx.x, wv = tid >> 6, lane = tid & 63;
  int clo = start_col[j], chi = start_col[j+1];
  int rlo = start_row[j], rhi = start_row[j+1];
  if (clo < 0) clo = 0; if (chi > E_EDGES) chi = E_EDGES; if (chi < clo) chi = clo;
  if (rlo < 0) rlo = 0; if (rhi > E_EDGES) rhi = E_EDGES; if (rhi < rlo) rhi = rlo;
  int nI = chi - clo, nO = rhi - rlo;
  int nS = half ? nO : nI;
  int nT = half ? nI : nO;
  int slo = half ? rlo : clo;
  int tlo = half ? clo : rlo;
  const int* slist = half ? list_row : list_col;
  const int* tlist = half ? list_col : list_row;
  if (nT == 0) return;
  int isbf = flg[0];

  if (nS <= DEG_CAP && nT <= DEG_CAP){
    int nS4 = (nS + 3) & ~3;
    if (tid < nS){
      int s = clampi(slist[slo+tid], E_EDGES);
      othS[tid] = clampi(half ? col[s] : row[s], N_NODES);
      eS[tid] = ldv(eattr, s, isbf);
      vS[tid][0]=vecn[s*4+0]; vS[tid][1]=vecn[s*4+1];
      vS[tid][2]=vecn[s*4+2]; vS[tid][3]=vecn[s*4+3];
    }
    if (tid < nT){
      int t = clampi(tlist[tlo+tid], E_EDGES);
      posT[tid] = clampi(pos_col[t], E_EDGES);
      vT[tid][0]=vecn[t*4+0]; vT[tid][1]=vecn[t*4+1];
      vT[tid][2]=vecn[t*4+2]; vT[tid][3]=vecn[t*4+3];
    }
    for (int i = tid; i < DEG_CAP*8; i += 256) ((float*)e64)[i] = 0.f;
    { uint4 z = {0,0,0,0};                       // zero bins pre-barrier (pad cols stay 0)
      ((uint4*)bins)[tid] = z; }
    __syncthreads();
    // stage source features as float: half=0 -> [x[other]|x[j]], half=1 -> [x[j]|x[other]]
    for (int cidx = tid; cidx < nS*64; cidx += 256){
      int si = cidx >> 6, f = cidx & 63;
      int lo_node = half ? j : othS[si];
      int hi_node = half ? othS[si] : j;
      int src = (f < 32) ? (lo_node*C_DIM + f) : (hi_node*C_DIM + f - 32);
      fS[si][f] = ldv(x, (size_t)src, isbf);
    }
    // zero pad rows [nS, nS4)
    for (int i = tid; i < (nS4 - nS)*64; i += 256)
      fS[nS + (i >> 6)][i & 63] = 0.f;
    // pair bins (+ eattr accumulation per (target, bin))
    for (int p = tid; p < nS*64; p += 256){
      int si = p >> 6, ti = p & 63;
      if (ti < nT){
        float dot = -(vS[si][0]*vT[ti][0] + vS[si][1]*vT[ti][1] + vS[si][2]*vT[ti][2]);
        float cv = dot / (vS[si][3]*vT[ti][3] + 1e-8f);
        int t = (cv<=cb1)+(cv<=cb2)+(cv<=cb3)+(cv<=-cb3)+(cv<=-cb2)+(cv<=-cb1);
        bins[ti][si] = (unsigned char)t;
        atomicAdd(&e64[ti][t], eS[si]);
      }
    }
    __syncthreads();
    for (int ti = wv; ti < nT; ti += 4){
      float S0=0,S1=0,S2=0,S3=0,S4=0,S5=0,S6=0;
      const unsigned* brow = (const unsigned*)bins[ti];
      for (int s4 = 0; s4 < nS4; s4 += 4){
        unsigned bb = brow[s4 >> 2];             // 4 bins, wave-uniform
        #pragma unroll
        for (int u = 0; u < 4; ++u){
          int t = (bb >> (8*u)) & 7;
          float val = fS[s4 + u][lane];          // pad rows are 0 -> harmless
          switch(t){
            case 0: S0+=val; break; case 1: S1+=val; break; case 2: S2+=val; break;
            case 3: S3+=val; break; case 4: S4+=val; break; case 5: S5+=val; break;
            default: S6+=val; break;
          }
        }
      }
      unsigned short* mrow = msg + (size_t)posT[ti]*KPH;
      mrow[0*65+lane]=f2bf(S0); mrow[1*65+lane]=f2bf(S1); mrow[2*65+lane]=f2bf(S2);
      mrow[3*65+lane]=f2bf(S3); mrow[4*65+lane]=f2bf(S4); mrow[5*65+lane]=f2bf(S5);
      mrow[6*65+lane]=f2bf(S6);
      if (lane < 7)  mrow[lane*65+64] = f2bf(e64[ti][lane]);
      if (lane < 25) mrow[455+lane] = 0;
    }
  } else {
    // degree > cap fallback: all-global (correct, ~never taken)
    for (int ti = wv; ti < nT; ti += 4){
      int te = clampi(tlist[tlo+ti], E_EDGES);
      float tx=vecn[te*4+0], ty=vecn[te*4+1], tz=vecn[te*4+2], tn=vecn[te*4+3];
      float S0=0,S1=0,S2=0,S3=0,S4=0,S5=0,S6=0,S64v=0;
      for (int si = 0; si < nS; ++si){
        int se = clampi(slist[slo+si], E_EDGES);
        float dot = -(vecn[se*4+0]*tx + vecn[se*4+1]*ty + vecn[se*4+2]*tz);
        float cv = dot / (vecn[se*4+3]*tn + 1e-8f);
        int tv = (cv<=cb1)+(cv<=cb2)+(cv<=cb3)+(cv<=-cb3)+(cv<=-cb2)+(cv<=-cb1);
        int t = __builtin_amdgcn_readfirstlane(tv);
        int oth = clampi(half ? col[se] : row[se], N_NODES);
        int lo_node = half ? j : oth;
        int hi_node = half ? oth : j;
        float val = (lane < 32) ? ldv(x, (size_t)lo_node*C_DIM+lane, isbf)
                                : ldv(x, (size_t)hi_node*C_DIM+lane-32, isbf);
        switch(t){
          case 0: S0+=val; break; case 1: S1+=val; break; case 2: S2+=val; break;
          case 3: S3+=val; break; case 4: S4+=val; break; case 5: S5+=val; break;
          default: S6+=val; break;
        }
        S64v += (lane == t) ? ldv(eattr, se, isbf) : 0.f;
      }
      unsigned short* mrow = msg + (size_t)clampi(pos_col[te], E_EDGES)*KPH;
      mrow[0*65+lane]=f2bf(S0); mrow[1*65+lane]=f2bf(S1); mrow[2*65+lane]=f2bf(S2);
      mrow[3*65+lane]=f2bf(S3); mrow[4*65+lane]=f2bf(S4); mrow[5*65+lane]=f2bf(S5);
      mrow[6*65+lane]=f2bf(S6);
      if (lane < 7)  mrow[lane*65+64] = f2bf(S64v);
      if (lane < 25) mrow[455+lane] = 0;
    }
  }
}

// ---------------- GEMM: B in LDS once, 3-deep A prefetch, single-phase epilogue ----------------
__global__ __launch_bounds__(256)
void k_gemm(const unsigned short* __restrict__ msg,
            const unsigned short* __restrict__ Wp,
            const void* __restrict__ bias,
            const int* __restrict__ flg,
            const int* __restrict__ node_of_pos,
            float* __restrict__ out_acc, int phase)
{
  __shared__ union {
    unsigned short Bs[64*512];     // 65536 B (60 of 64 chunk slots used per row)
    float seg[256][66];            // 67584 B, reused after K-loop
  } sh;
  __shared__ int nids[256];

  int tid = threadIdx.x;
  int w = tid >> 6, lane = tid & 63;
  int lrow = lane & 15, q = lane >> 4;
  int m0 = blockIdx.x * 256;
  int ch = blockIdx.y;               // 0/1: output cols [ch*64, ch*64+64)

  nids[tid] = clampi(node_of_pos[m0 + tid], N_NODES);

  // A prologue: issue 3 k-steps of loads early (overlaps with B staging)
  const unsigned short* abase = msg + (size_t)(m0 + w*64 + lrow)*KPH + q*8;
  short8 apf[3][4];
  #pragma unroll
  for (int d = 0; d < 3; ++d)
    #pragma unroll
    for (int rf = 0; rf < 4; ++rf)
      apf[d][rf] = *(const short8*)(abase + (size_t)rf*16*KPH + d*32);

  // stage B once: 64 rows x 60 chunks of 16B
  #pragma unroll
  for (int i = 0; i < 15; ++i){
    int idx = tid + i*256;
    int rr = idx / 60, cc = idx - rr*60;
    const uint4* gq = (const uint4*)(Wp + (size_t)(ch*64 + rr)*KPH + cc*8);
    *(uint4*)(sh.Bs + rr*512 + ((cc ^ (rr & 7))*8)) = *gq;
  }
  __syncthreads();

  f32x4 acc[4][4];
  #pragma unroll
  for (int rf = 0; rf < 4; ++rf)
    #pragma unroll
    for (int nf = 0; nf < 4; ++nf) acc[rf][nf] = (f32x4)0.f;

  #pragma unroll
  for (int k0i = 0; k0i < 15; ++k0i){
    int cur = k0i % 3;
    int c = k0i*4 + q;               // B chunk index 0..59
    #pragma unroll
    for (int nf = 0; nf < 4; ++nf){
      int rb = nf*16 + lrow;
      short8 bfr = *(const short8*)(sh.Bs + rb*512 + ((c ^ (rb & 7))*8));
      #pragma unroll
      for (int rf = 0; rf < 4; ++rf)
        acc[rf][nf] = __builtin_amdgcn_mfma_f32_16x16x32_bf16(apf[cur][rf], bfr, acc[rf][nf], 0, 0, 0);
    }
    if (k0i + 3 < 15){               // refill just-consumed buffer (3-step window)
      #pragma unroll
      for (int rf = 0; rf < 4; ++rf)
        apf[cur][rf] = *(const short8*)(abase + (size_t)rf*16*KPH + (k0i+3)*32);
    }
  }

  int isbf = flg[0];
  float bvs[4];
  #pragma unroll
  for (int nf = 0; nf < 4; ++nf)
    bvs[nf] = phase ? 0.f : ldv(bias, ch*64 + nf*16 + lrow, isbf);

  // single-phase epilogue: all waves dump fragments, then 4 groups reduce concurrently
  __syncthreads();                   // Bs dead from here
  #pragma unroll
  for (int rf = 0; rf < 4; ++rf)
    #pragma unroll
    for (int r = 0; r < 4; ++r){
      int m = w*64 + rf*16 + q*4 + r;
      #pragma unroll
      for (int nf = 0; nf < 4; ++nf)
        sh.seg[m][nf*16 + lrow] = acc[rf][nf][r] + bvs[nf];
    }
  __syncthreads();
  {
    int o = tid & 63, g = tid >> 6;  // 4 groups x 64 rows
    int base = g*64;
    float s = 0.f;
    int curn = nids[base];
    for (int r = 0; r < 64; ++r){
      int m = base + r;
      int nid = nids[m];
      if (nid != curn){
        atomicAdd(out_acc + (size_t)curn*OUT_DIM + ch*64 + o, s);
        s = 0.f; curn = nid;
      }
      s += sh.seg[m][o];
    }
    atomicAdd(out_acc + (size_t)curn*OUT_DIM + ch*64 + o, s);
  }
}

// ---------------- convert out_acc -> d_out per flag ----------------
__global__ void k_out(const float* __restrict__ acc, void* __restrict__ outp,
                      const int* __restrict__ flg){
  int i = blockIdx.x*blockDim.x + threadIdx.x;
  if (i >= N_NODES*OUT_DIM) return;
  if (flg[0]) ((unsigned short*)outp)[i] = f2bf(acc[i]);
  else        ((float*)outp)[i] = acc[i];
}

extern "C" void kernel_launch(void* const* d_in, const int* in_sizes, int n_in,
                              void* d_out, int out_size, void* d_ws, size_t ws_size,
                              hipStream_t stream)
{
  const void* x     = d_in[0];
  const void* eattr = d_in[1];
  const void* pos   = d_in[2];
  const void* W     = d_in[3];
  const void* bmsg  = d_in[4];
  const int* eidx = (const int*)d_in[5];
  const int* row = eidx;
  const int* col = eidx + E_EDGES;

  char* ws = (char*)d_ws;
  size_t off = 0;
  auto alloc = [&](size_t b){ size_t o = off; off += (b + 255) & ~(size_t)255; return o; };

  int* dflag        = (int*)(ws + alloc(256));
  float* vecn       = (float*)(ws + alloc((size_t)E_EDGES*16));
  int* cnt          = (int*)(ws + alloc((size_t)2*N_NODES*4));
  int* start2       = (int*)(ws + alloc((size_t)2*(N_NODES+1)*4));
  int* fill2        = (int*)(ws + alloc((size_t)2*N_NODES*4));
  int* segsum       = (int*)(ws + alloc((size_t)2*NSEG*4));
  int* list_row     = (int*)(ws + alloc((size_t)E_EDGES*4));
  int* list_col     = (int*)(ws + alloc((size_t)E_EDGES*4));
  int* pos_col      = (int*)(ws + alloc((size_t)E_EDGES*4));
  int* node_of_pos  = (int*)(ws + alloc((size_t)E_EDGES*4));
  unsigned short* Wp = (unsigned short*)(ws + alloc((size_t)2*OUT_DIM*KPH*2));
  float* out_acc    = (float*)(ws + alloc((size_t)N_NODES*OUT_DIM*4));
  unsigned short* msg = (unsigned short*)(ws + alloc((size_t)E_EDGES*KPH*2));
  (void)off; // ~170 MB total, fits the 256 MiB workspace

  unsigned short* Wp_in  = Wp;
  unsigned short* Wp_out = Wp + (size_t)OUT_DIM*KPH;

  k_sniff<<<1, 256, 0, stream>>>(x, dflag);
  k_zero<<<(2*N_NODES+255)/256, 256, 0, stream>>>(cnt, 2*N_NODES);
  k_zero<<<(N_NODES*OUT_DIM+255)/256, 256, 0, stream>>>((int*)out_acc, N_NODES*OUT_DIM);
  k_build<<<(E_EDGES+255)/256, 256, 0, stream>>>(pos, row, col, vecn, cnt, dflag);
  k_scan1<<<2*NSEG, SEG, 0, stream>>>(cnt, start2, segsum);
  k_scan2<<<1, 64, 0, stream>>>(segsum);
  k_scan3<<<2*NSEG, SEG, 0, stream>>>(start2, fill2, segsum);
  k_scatter<<<(E_EDGES+255)/256, 256, 0, stream>>>(row, col, fill2,
                                                   list_row, list_col, pos_col, node_of_pos);
  k_packw<<<(2*OUT_DIM*KPH+255)/256, 256, 0, stream>>>(W, Wp, dflag);

  // phase 1: in-halves
  k_msg_node<<<N_NODES, 256, 0, stream>>>(x, eattr, vecn, row, col, start2,
                                          list_row, list_col, pos_col, msg, dflag, 0);
  k_gemm<<<dim3(E_EDGES/256, 2), 256, 0, stream>>>(msg, Wp_in, bmsg, dflag,
                                                   node_of_pos, out_acc, 0);
  // phase 2: out-halves (reuse msg buffer)
  k_msg_node<<<N_NODES, 256, 0, stream>>>(x, eattr, vecn, row, col, start2,
                                          list_row, list_col, pos_col, msg, dflag, 1);
  k_gemm<<<dim3(E_EDGES/256, 2), 256, 0, stream>>>(msg, Wp_out, bmsg, dflag,
                                                   node_of_pos, out_acc, 1);

  k_out<<<(N_NODES*OUT_DIM+255)/256, 256, 0, stream>>>(out_acc, d_out, dflag);
}

// Round 13
// 420.664 us; speedup vs baseline: 1.0906x; 1.0906x over previous
//
#include <hip/hip_runtime.h>
#include <stdint.h>

#define N_NODES 20000
#define E_EDGES 160000
#define C_DIM 32
#define OUT_DIM 128
#define K_REAL 910
#define KPH 480           // padded per-half K (455 real + 25 zeros), 15 x 32
#define DEG_CAP 64
#define SEG 1024
#define NSEG 20           // ceil(20000/1024)

typedef __attribute__((ext_vector_type(4))) float f32x4;
typedef __attribute__((ext_vector_type(8))) short short8;

__device__ __forceinline__ float bf2f(unsigned short u){
  union { unsigned int i; float f; } v; v.i = ((unsigned int)u) << 16; return v.f;
}
__device__ __forceinline__ unsigned short f2bf(float f){
  union { float f; unsigned int i; } v; v.f = f;
  unsigned int i = v.i;
  unsigned int r = (i + 0x7FFFu + ((i >> 16) & 1u)) >> 16;
  return (unsigned short)r;
}
__device__ __forceinline__ float ldv(const void* p, size_t i, int isbf){
  return isbf ? bf2f(((const unsigned short*)p)[i]) : ((const float*)p)[i];
}
__device__ __forceinline__ int clampi(int v, int hi){  // [0, hi)
  return ((unsigned)v < (unsigned)hi) ? v : 0;
}

// ---------------- dtype sniffer ----------------
__global__ void k_sniff(const void* xraw, int* flag){
  const unsigned short* xu = (const unsigned short*)xraw;
  __shared__ int s_bad;
  int tid = threadIdx.x;
  if (tid == 0) s_bad = 0;
  __syncthreads();
  float v = bf2f(xu[tid * 2499]);
  if (!(fabsf(v) < 100.0f)) s_bad = 1;
  __syncthreads();
  if (tid == 0) flag[0] = s_bad ? 0 : 1; // 1 = bf16, 0 = fp32
}

__global__ void k_zero(int* p, int n){
  int i = blockIdx.x*blockDim.x + threadIdx.x;
  if (i < n) p[i] = 0;
}

// ---------------- edge vectors + degree histograms ----------------
__global__ void k_build(const void* __restrict__ pos,
                        const int* __restrict__ row, const int* __restrict__ col,
                        float* __restrict__ vecn, int* __restrict__ cnt,
                        const int* __restrict__ flg)
{
  int e = blockIdx.x*blockDim.x + threadIdx.x;
  if (e >= E_EDGES) return;
  int isbf = flg[0];
  int r = clampi(row[e], N_NODES), c = clampi(col[e], N_NODES);
  float vx = ldv(pos, (size_t)c*3+0, isbf) - ldv(pos, (size_t)r*3+0, isbf);
  float vy = ldv(pos, (size_t)c*3+1, isbf) - ldv(pos, (size_t)r*3+1, isbf);
  float vz = ldv(pos, (size_t)c*3+2, isbf) - ldv(pos, (size_t)r*3+2, isbf);
  float nn = sqrtf(vx*vx + vy*vy + vz*vz);
  f32x4 vv; vv[0]=vx; vv[1]=vy; vv[2]=vz; vv[3]=nn;
  *(f32x4*)(vecn + (size_t)e*4) = vv;
  atomicAdd(cnt + r, 1);
  atomicAdd(cnt + N_NODES + c, 1);
}

// ---------------- 3-phase exclusive scan over cnt[2N] ----------------
__global__ void k_scan1(const int* __restrict__ cnt, int* __restrict__ start2,
                        int* __restrict__ segsum){
  __shared__ int buf[SEG];
  int b = blockIdx.x, arr = b / NSEG, seg = b - arr*NSEG;
  const int* cntp = cnt + (size_t)arr*N_NODES;
  int* startp = start2 + (size_t)arr*(N_NODES+1);
  int tid = threadIdx.x;
  int i = seg*SEG + tid;
  int v = (i < N_NODES) ? cntp[i] : 0;
  buf[tid] = v;
  __syncthreads();
  for (int off = 1; off < SEG; off <<= 1){
    int t = (tid >= off) ? buf[tid-off] : 0;
    __syncthreads();
    buf[tid] += t;
    __syncthreads();
  }
  if (i < N_NODES) startp[i] = buf[tid] - v;
  if (tid == SEG-1) segsum[b] = buf[tid];
}
__global__ void k_scan2(int* segsum){
  int tid = threadIdx.x;
  if (tid < 2){
    int run = 0;
    for (int s = 0; s < NSEG; ++s){
      int v = segsum[tid*NSEG+s]; segsum[tid*NSEG+s] = run; run += v;
    }
  }
}
__global__ void k_scan3(int* __restrict__ start2, int* __restrict__ fill2,
                        const int* __restrict__ segsum){
  int b = blockIdx.x, arr = b / NSEG, seg = b - arr*NSEG;
  int* startp = start2 + (size_t)arr*(N_NODES+1);
  int* fillp  = fill2  + (size_t)arr*N_NODES;
  int tid = threadIdx.x;
  int i = seg*SEG + tid;
  int add = segsum[b];
  if (i < N_NODES){ int s = startp[i] + add; startp[i] = s; fillp[i] = s; }
  if (b == 0 && tid == 0){
    start2[N_NODES] = E_EDGES;
    start2[(N_NODES+1) + N_NODES] = E_EDGES;
  }
}

// ---------------- scatter edge ids into CSR lists (+ inverse col perm + node of pos) ----------------
__global__ void k_scatter(const int* __restrict__ row, const int* __restrict__ col,
                          int* fill2, int* list_row, int* list_col,
                          int* pos_col, int* node_of_pos)
{
  int e = blockIdx.x*blockDim.x + threadIdx.x;
  if (e >= E_EDGES) return;
  int r = clampi(row[e], N_NODES), c = clampi(col[e], N_NODES);
  int p = atomicAdd(fill2 + r, 1);
  if ((unsigned)p < E_EDGES) list_row[p] = e;
  int q = atomicAdd(fill2 + N_NODES + c, 1);
  if ((unsigned)q < E_EDGES){ list_col[q] = e; node_of_pos[q] = c; }
  pos_col[e] = clampi(q, E_EDGES);
}

// ---------------- pack W into two padded halves Wp[half][128][KPH] ----------------
__global__ void k_packw(const void* __restrict__ W, unsigned short* __restrict__ Wp,
                        const int* __restrict__ flg){
  int isbf = flg[0];
  int i = blockIdx.x*blockDim.x + threadIdx.x;
  if (i >= 2*OUT_DIM*KPH) return;
  int half = i / (OUT_DIM*KPH);
  int rem = i - half*OUT_DIM*KPH;
  int o = rem / KPH, kp = rem - o*KPH;
  float v = 0.f;
  if (kp < 455){
    int t = kp/65, f = kp - t*65;
    v = ldv(W, (size_t)o*K_REAL + (2*t + half)*65 + f, isbf);
  }
  Wp[i] = f2bf(v);
}

// ---------------- node-centric message build (bf16 fS = 8 blocks/CU, u32 bins) ----------------
__global__ __launch_bounds__(256)
void k_msg_node(const void* __restrict__ x, const void* __restrict__ eattr,
                const float* __restrict__ vecn,
                const int* __restrict__ row, const int* __restrict__ col,
                const int* __restrict__ start2,
                const int* __restrict__ list_row, const int* __restrict__ list_col,
                const int* __restrict__ pos_col,
                unsigned short* __restrict__ msg,
                const int* __restrict__ flg, int half)
{
  __shared__ int posT[DEG_CAP];
  __shared__ int othS[DEG_CAP];
  __shared__ float vS[DEG_CAP][4], vT[DEG_CAP][4];
  __shared__ float eS[DEG_CAP];
  __shared__ unsigned short fS[DEG_CAP][64];       // bf16: keeps LDS at 17.4 KB -> 8 blocks/CU
  __shared__ float e64[DEG_CAP][8];
  __shared__ unsigned char bins[DEG_CAP][DEG_CAP]; // [target][source], 0-padded

  const float cb1 = 0.9009688679f, cb2 = 0.6234898019f, cb3 = 0.2225209340f;
  const int* start_row = start2;
  const int* start_col = start2 + (N_NODES+1);
  int j = blockIdx.x;
  int tid = threadIdx.x, wv = tid >> 6, lane = tid & 63;
  int clo = start_col[j], chi = start_col[j+1];
  int rlo = start_row[j], rhi = start_row[j+1];
  if (clo < 0) clo = 0; if (chi > E_EDGES) chi = E_EDGES; if (chi < clo) chi = clo;
  if (rlo < 0) rlo = 0; if (rhi > E_EDGES) rhi = E_EDGES; if (rhi < rlo) rhi = rlo;
  int nI = chi - clo, nO = rhi - rlo;
  int nS = half ? nO : nI;
  int nT = half ? nI : nO;
  int slo = half ? rlo : clo;
  int tlo = half ? clo : rlo;
  const int* slist = half ? list_row : list_col;
  const int* tlist = half ? list_col : list_row;
  if (nT == 0) return;
  int isbf = flg[0];

  if (nS <= DEG_CAP && nT <= DEG_CAP){
    int nS4 = (nS + 3) & ~3;
    if (tid < nS){
      int s = clampi(slist[slo+tid], E_EDGES);
      othS[tid] = clampi(half ? col[s] : row[s], N_NODES);
      eS[tid] = ldv(eattr, s, isbf);
      vS[tid][0]=vecn[s*4+0]; vS[tid][1]=vecn[s*4+1];
      vS[tid][2]=vecn[s*4+2]; vS[tid][3]=vecn[s*4+3];
    }
    if (tid < nT){
      int t = clampi(tlist[tlo+tid], E_EDGES);
      posT[tid] = clampi(pos_col[t], E_EDGES);
      vT[tid][0]=vecn[t*4+0]; vT[tid][1]=vecn[t*4+1];
      vT[tid][2]=vecn[t*4+2]; vT[tid][3]=vecn[t*4+3];
    }
    for (int i = tid; i < DEG_CAP*8; i += 256) ((float*)e64)[i] = 0.f;
    { uint4 z = {0,0,0,0};                       // zero bins (pad cols read as t=0)
      ((uint4*)bins)[tid] = z; }
    __syncthreads();
    // stage source features: half=0 -> [x[other]|x[j]], half=1 -> [x[j]|x[other]]
    for (int cidx = tid; cidx < nS*64; cidx += 256){
      int si = cidx >> 6, f = cidx & 63;
      int lo_node = half ? j : othS[si];
      int hi_node = half ? othS[si] : j;
      int src = (f < 32) ? (lo_node*C_DIM + f) : (hi_node*C_DIM + f - 32);
      fS[si][f] = f2bf(ldv(x, (size_t)src, isbf));
    }
    // zero pad rows [nS, nS4) so pad (t=0) adds 0 to S0
    for (int i = tid; i < (nS4 - nS)*64; i += 256)
      fS[nS + (i >> 6)][i & 63] = 0;
    // pair bins (+ eattr accumulation per (target, bin))
    for (int p = tid; p < nS*64; p += 256){
      int si = p >> 6, ti = p & 63;
      if (ti < nT){
        float dot = -(vS[si][0]*vT[ti][0] + vS[si][1]*vT[ti][1] + vS[si][2]*vT[ti][2]);
        float cv = dot / (vS[si][3]*vT[ti][3] + 1e-8f);
        int t = (cv<=cb1)+(cv<=cb2)+(cv<=cb3)+(cv<=-cb3)+(cv<=-cb2)+(cv<=-cb1);
        bins[ti][si] = (unsigned char)t;
        atomicAdd(&e64[ti][t], eS[si]);
      }
    }
    __syncthreads();
    for (int ti = wv; ti < nT; ti += 4){
      float S0=0,S1=0,S2=0,S3=0,S4=0,S5=0,S6=0;
      const unsigned* brow = (const unsigned*)bins[ti];
      for (int s4 = 0; s4 < nS4; s4 += 4){
        unsigned bb = brow[s4 >> 2];             // 4 bins per u32, wave-uniform
        #pragma unroll
        for (int u = 0; u < 4; ++u){
          int t = (bb >> (8*u)) & 7;
          float val = bf2f(fS[s4 + u][lane]);    // pad rows are 0
          switch(t){
            case 0: S0+=val; break; case 1: S1+=val; break; case 2: S2+=val; break;
            case 3: S3+=val; break; case 4: S4+=val; break; case 5: S5+=val; break;
            default: S6+=val; break;
          }
        }
      }
      unsigned short* mrow = msg + (size_t)posT[ti]*KPH;
      mrow[0*65+lane]=f2bf(S0); mrow[1*65+lane]=f2bf(S1); mrow[2*65+lane]=f2bf(S2);
      mrow[3*65+lane]=f2bf(S3); mrow[4*65+lane]=f2bf(S4); mrow[5*65+lane]=f2bf(S5);
      mrow[6*65+lane]=f2bf(S6);
      if (lane < 7)  mrow[lane*65+64] = f2bf(e64[ti][lane]);
      if (lane < 25) mrow[455+lane] = 0;
    }
  } else {
    // degree > cap fallback: all-global (correct, ~never taken)
    for (int ti = wv; ti < nT; ti += 4){
      int te = clampi(tlist[tlo+ti], E_EDGES);
      float tx=vecn[te*4+0], ty=vecn[te*4+1], tz=vecn[te*4+2], tn=vecn[te*4+3];
      float S0=0,S1=0,S2=0,S3=0,S4=0,S5=0,S6=0,S64v=0;
      for (int si = 0; si < nS; ++si){
        int se = clampi(slist[slo+si], E_EDGES);
        float dot = -(vecn[se*4+0]*tx + vecn[se*4+1]*ty + vecn[se*4+2]*tz);
        float cv = dot / (vecn[se*4+3]*tn + 1e-8f);
        int tv = (cv<=cb1)+(cv<=cb2)+(cv<=cb3)+(cv<=-cb3)+(cv<=-cb2)+(cv<=-cb1);
        int t = __builtin_amdgcn_readfirstlane(tv);
        int oth = clampi(half ? col[se] : row[se], N_NODES);
        int lo_node = half ? j : oth;
        int hi_node = half ? oth : j;
        float val = (lane < 32) ? ldv(x, (size_t)lo_node*C_DIM+lane, isbf)
                                : ldv(x, (size_t)hi_node*C_DIM+lane-32, isbf);
        switch(t){
          case 0: S0+=val; break; case 1: S1+=val; break; case 2: S2+=val; break;
          case 3: S3+=val; break; case 4: S4+=val; break; case 5: S5+=val; break;
          default: S6+=val; break;
        }
        S64v += (lane == t) ? ldv(eattr, se, isbf) : 0.f;
      }
      unsigned short* mrow = msg + (size_t)clampi(pos_col[te], E_EDGES)*KPH;
      mrow[0*65+lane]=f2bf(S0); mrow[1*65+lane]=f2bf(S1); mrow[2*65+lane]=f2bf(S2);
      mrow[3*65+lane]=f2bf(S3); mrow[4*65+lane]=f2bf(S4); mrow[5*65+lane]=f2bf(S5);
      mrow[6*65+lane]=f2bf(S6);
      if (lane < 7)  mrow[lane*65+64] = f2bf(S64v);
      if (lane < 25) mrow[455+lane] = 0;
    }
  }
}

// ---------------- GEMM: B in LDS once, 3-deep A prefetch, single-phase epilogue ----------------
__global__ __launch_bounds__(256)
void k_gemm(const unsigned short* __restrict__ msg,
            const unsigned short* __restrict__ Wp,
            const void* __restrict__ bias,
            const int* __restrict__ flg,
            const int* __restrict__ node_of_pos,
            float* __restrict__ out_acc, int phase)
{
  __shared__ union {
    unsigned short Bs[64*512];     // 65536 B (60 of 64 chunk slots used per row)
    float seg[256][66];            // 67584 B, reused after K-loop
  } sh;
  __shared__ int nids[256];

  int tid = threadIdx.x;
  int w = tid >> 6, lane = tid & 63;
  int lrow = lane & 15, q = lane >> 4;
  int m0 = blockIdx.x * 256;
  int ch = blockIdx.y;               // 0/1: output cols [ch*64, ch*64+64)

  nids[tid] = clampi(node_of_pos[m0 + tid], N_NODES);

  // A prologue: issue 3 k-steps of loads early (overlaps with B staging)
  const unsigned short* abase = msg + (size_t)(m0 + w*64 + lrow)*KPH + q*8;
  short8 apf[3][4];
  #pragma unroll
  for (int d = 0; d < 3; ++d)
    #pragma unroll
    for (int rf = 0; rf < 4; ++rf)
      apf[d][rf] = *(const short8*)(abase + (size_t)rf*16*KPH + d*32);

  // stage B once: 64 rows x 60 chunks of 16B
  #pragma unroll
  for (int i = 0; i < 15; ++i){
    int idx = tid + i*256;
    int rr = idx / 60, cc = idx - rr*60;
    const uint4* gq = (const uint4*)(Wp + (size_t)(ch*64 + rr)*KPH + cc*8);
    *(uint4*)(sh.Bs + rr*512 + ((cc ^ (rr & 7))*8)) = *gq;
  }
  __syncthreads();

  f32x4 acc[4][4];
  #pragma unroll
  for (int rf = 0; rf < 4; ++rf)
    #pragma unroll
    for (int nf = 0; nf < 4; ++nf) acc[rf][nf] = (f32x4)0.f;

  #pragma unroll
  for (int k0i = 0; k0i < 15; ++k0i){
    int cur = k0i % 3;
    int c = k0i*4 + q;               // B chunk index 0..59
    #pragma unroll
    for (int nf = 0; nf < 4; ++nf){
      int rb = nf*16 + lrow;
      short8 bfr = *(const short8*)(sh.Bs + rb*512 + ((c ^ (rb & 7))*8));
      #pragma unroll
      for (int rf = 0; rf < 4; ++rf)
        acc[rf][nf] = __builtin_amdgcn_mfma_f32_16x16x32_bf16(apf[cur][rf], bfr, acc[rf][nf], 0, 0, 0);
    }
    if (k0i + 3 < 15){               // refill just-consumed buffer (3-step window)
      #pragma unroll
      for (int rf = 0; rf < 4; ++rf)
        apf[cur][rf] = *(const short8*)(abase + (size_t)rf*16*KPH + (k0i+3)*32);
    }
  }

  int isbf = flg[0];
  float bvs[4];
  #pragma unroll
  for (int nf = 0; nf < 4; ++nf)
    bvs[nf] = phase ? 0.f : ldv(bias, ch*64 + nf*16 + lrow, isbf);

  // single-phase epilogue: all waves dump fragments, then 4 groups reduce concurrently
  __syncthreads();                   // Bs dead from here
  #pragma unroll
  for (int rf = 0; rf < 4; ++rf)
    #pragma unroll
    for (int r = 0; r < 4; ++r){
      int m = w*64 + rf*16 + q*4 + r;
      #pragma unroll
      for (int nf = 0; nf < 4; ++nf)
        sh.seg[m][nf*16 + lrow] = acc[rf][nf][r] + bvs[nf];
    }
  __syncthreads();
  {
    int o = tid & 63, g = tid >> 6;  // 4 groups x 64 rows
    int base = g*64;
    float s = 0.f;
    int curn = nids[base];
    for (int r = 0; r < 64; ++r){
      int m = base + r;
      int nid = nids[m];
      if (nid != curn){
        atomicAdd(out_acc + (size_t)curn*OUT_DIM + ch*64 + o, s);
        s = 0.f; curn = nid;
      }
      s += sh.seg[m][o];
    }
    atomicAdd(out_acc + (size_t)curn*OUT_DIM + ch*64 + o, s);
  }
}

// ---------------- convert out_acc -> d_out per flag ----------------
__global__ void k_out(const float* __restrict__ acc, void* __restrict__ outp,
                      const int* __restrict__ flg){
  int i = blockIdx.x*blockDim.x + threadIdx.x;
  if (i >= N_NODES*OUT_DIM) return;
  if (flg[0]) ((unsigned short*)outp)[i] = f2bf(acc[i]);
  else        ((float*)outp)[i] = acc[i];
}

extern "C" void kernel_launch(void* const* d_in, const int* in_sizes, int n_in,
                              void* d_out, int out_size, void* d_ws, size_t ws_size,
                              hipStream_t stream)
{
  const void* x     = d_in[0];
  const void* eattr = d_in[1];
  const void* pos   = d_in[2];
  const void* W     = d_in[3];
  const void* bmsg  = d_in[4];
  const int* eidx = (const int*)d_in[5];
  const int* row = eidx;
  const int* col = eidx + E_EDGES;

  char* ws = (char*)d_ws;
  size_t off = 0;
  auto alloc = [&](size_t b){ size_t o = off; off += (b + 255) & ~(size_t)255; return o; };

  int* dflag        = (int*)(ws + alloc(256));
  float* vecn       = (float*)(ws + alloc((size_t)E_EDGES*16));
  int* cnt          = (int*)(ws + alloc((size_t)2*N_NODES*4));
  int* start2       = (int*)(ws + alloc((size_t)2*(N_NODES+1)*4));
  int* fill2        = (int*)(ws + alloc((size_t)2*N_NODES*4));
  int* segsum       = (int*)(ws + alloc((size_t)2*NSEG*4));
  int* list_row     = (int*)(ws + alloc((size_t)E_EDGES*4));
  int* list_col     = (int*)(ws + alloc((size_t)E_EDGES*4));
  int* pos_col      = (int*)(ws + alloc((size_t)E_EDGES*4));
  int* node_of_pos  = (int*)(ws + alloc((size_t)E_EDGES*4));
  unsigned short* Wp = (unsigned short*)(ws + alloc((size_t)2*OUT_DIM*KPH*2));
  float* out_acc    = (float*)(ws + alloc((size_t)N_NODES*OUT_DIM*4));
  unsigned short* msg = (unsigned short*)(ws + alloc((size_t)E_EDGES*KPH*2));
  (void)off; // ~170 MB total, fits the 256 MiB workspace

  unsigned short* Wp_in  = Wp;
  unsigned short* Wp_out = Wp + (size_t)OUT_DIM*KPH;

  k_sniff<<<1, 256, 0, stream>>>(x, dflag);
  k_zero<<<(2*N_NODES+255)/256, 256, 0, stream>>>(cnt, 2*N_NODES);
  k_zero<<<(N_NODES*OUT_DIM+255)/256, 256, 0, stream>>>((int*)out_acc, N_NODES*OUT_DIM);
  k_build<<<(E_EDGES+255)/256, 256, 0, stream>>>(pos, row, col, vecn, cnt, dflag);
  k_scan1<<<2*NSEG, SEG, 0, stream>>>(cnt, start2, segsum);
  k_scan2<<<1, 64, 0, stream>>>(segsum);
  k_scan3<<<2*NSEG, SEG, 0, stream>>>(start2, fill2, segsum);
  k_scatter<<<(E_EDGES+255)/256, 256, 0, stream>>>(row, col, fill2,
                                                   list_row, list_col, pos_col, node_of_pos);
  k_packw<<<(2*OUT_DIM*KPH+255)/256, 256, 0, stream>>>(W, Wp, dflag);

  // phase 1: in-halves
  k_msg_node<<<N_NODES, 256, 0, stream>>>(x, eattr, vecn, row, col, start2,
                                          list_row, list_col, pos_col, msg, dflag, 0);
  k_gemm<<<dim3(E_EDGES/256, 2), 256, 0, stream>>>(msg, Wp_in, bmsg, dflag,
                                                   node_of_pos, out_acc, 0);
  // phase 2: out-halves (reuse msg buffer)
  k_msg_node<<<N_NODES, 256, 0, stream>>>(x, eattr, vecn, row, col, start2,
                                          list_row, list_col, pos_col, msg, dflag, 1);
  k_gemm<<<dim3(E_EDGES/256, 2), 256, 0, stream>>>(msg, Wp_out, bmsg, dflag,
                                                   node_of_pos, out_acc, 1);

  k_out<<<(N_NODES*OUT_DIM+255)/256, 256, 0, stream>>>(out_acc, d_out, dflag);
}